// Round 12
// baseline (597.177 us; speedup 1.0000x reference)
//
#include <hip/hip_runtime.h>
#include <hip/hip_bf16.h>

// Problem constants
#define NN   20000          // nodes
#define DIN_ 92             // atom feature dim
#define CC   128            // hidden dim
#define EE   640000         // edges (self loops handled explicitly)
#define BN_EPS 1e-5f
#define NEG_INF (-3.0e38f)

typedef short short8 __attribute__((ext_vector_type(8)));
typedef float floatx4 __attribute__((ext_vector_type(4)));

// ---------------------------------------------------------------------------
// Dual-dtype helpers: flags[0]=1 -> external floats are fp32 (else bf16)
//                     flags[1]=1 -> edge_index is int64 (else int32)
// ---------------------------------------------------------------------------
static __device__ __forceinline__ float b2f(__hip_bfloat16 v) { return __bfloat162float(v); }
static __device__ __forceinline__ float ldf(const void* p, int i, int f32) {
    return f32 ? ((const float*)p)[i]
               : __bfloat162float(((const __hip_bfloat16*)p)[i]);
}
static __device__ __forceinline__ void stf(void* p, int i, float v, int f32) {
    if (f32) ((float*)p)[i] = v;
    else     ((__hip_bfloat16*)p)[i] = __float2bfloat16(v);
}
static __device__ __forceinline__ float leaky02(float x) { return x > 0.f ? x : 0.2f * x; }

// bf16 decode via bit ops (bf16 = top half of fp32)
static __device__ __forceinline__ float2 bfp(unsigned w) {
    return make_float2(__uint_as_float(w << 16), __uint_as_float(w & 0xffff0000u));
}
static __device__ __forceinline__ float4 bf4(unsigned x, unsigned y) {
    return make_float4(__uint_as_float(x << 16), __uint_as_float(x & 0xffff0000u),
                       __uint_as_float(y << 16), __uint_as_float(y & 0xffff0000u));
}
static __device__ __forceinline__ uint2 f4bf(float4 v) {
    union { uint2 u; __hip_bfloat16 b[4]; } x;
    x.b[0] = __float2bfloat16(v.x); x.b[1] = __float2bfloat16(v.y);
    x.b[2] = __float2bfloat16(v.z); x.b[3] = __float2bfloat16(v.w);
    return x.u;
}
static __device__ __forceinline__ unsigned f2bf(float2 v) {
    union { unsigned u; __hip_bfloat16 b[2]; } x;
    x.b[0] = __float2bfloat16(v.x); x.b[1] = __float2bfloat16(v.y);
    return x.u;
}

// ---------------------------------------------------------------------------
// Runtime dtype detection
// ---------------------------------------------------------------------------
__global__ void detect_kernel(const unsigned int* __restrict__ x0,
                              const unsigned int* __restrict__ ei,
                              int* __restrict__ flags)
{
    __shared__ int cnt_band, cnt_zero;
    if (threadIdx.x == 0) { cnt_band = 0; cnt_zero = 0; }
    __syncthreads();
    unsigned w  = x0[threadIdx.x];
    unsigned eb = ((w & 0xFFFFu) >> 7) & 0xFFu;
    if (eb >= 90u && eb <= 140u) atomicAdd(&cnt_band, 1);
    if (ei[2 * threadIdx.x + 1] == 0u) atomicAdd(&cnt_zero, 1);
    __syncthreads();
    if (threadIdx.x == 0) {
        flags[0] = (cnt_band < 200) ? 1 : 0;   // 1 = fp32
        flags[1] = (cnt_zero >= 250) ? 1 : 0;  // 1 = int64
    }
}

// ---------------------------------------------------------------------------
// Merged conversion: transposed bf16 weights + padded bf16 node features
// ---------------------------------------------------------------------------
#define R0_ 12288
#define R1_ (R0_ + 16384)
#define R2_ (R1_ + 16384)
#define R3_ (R2_ + 16384)
#define R4_ (R3_ + 16384)
#define R5_ (R4_ + 32768)
#define R6_ (R5_ + 32768)          // 143360 weight elements
#define TCVT (R6_ + NN * 96)       // + node features

__global__ void cvt_all_kernel(const void* __restrict__ w_emb, const void* __restrict__ w1,
                               const void* __restrict__ w2, const void* __restrict__ wmu,
                               const void* __restrict__ wvar, const void* __restrict__ wgat,
                               const void* __restrict__ wdec, const void* __restrict__ xin,
                               __hip_bfloat16* __restrict__ dst, const int* __restrict__ flags)
{
    const int f32 = flags[0];
    int i = blockIdx.x * blockDim.x + threadIdx.x;
    if (i >= TCVT) return;
    float v;
    if (i < R0_) {
        int n = i / 96, k = i - n * 96;
        v = (k < DIN_) ? ldf(w_emb, k * 128 + n, f32) : 0.f;
    } else if (i < R1_) {
        int j = i - R0_; int n = j >> 7, k = j & 127; v = ldf(w1, k * 128 + n, f32);
    } else if (i < R2_) {
        int j = i - R1_; int n = j >> 7, k = j & 127; v = ldf(w2, k * 128 + n, f32);
    } else if (i < R3_) {
        int j = i - R2_; int n = j >> 7, k = j & 127; v = ldf(wmu, k * 128 + n, f32);
    } else if (i < R4_) {
        int j = i - R3_; int n = j >> 7, k = j & 127; v = ldf(wvar, k * 128 + n, f32);
    } else if (i < R5_) {
        int j = i - R4_; int n = j >> 7, k = j & 127; v = ldf(wgat, k * 256 + n, f32);
    } else if (i < R6_) {
        int j = i - R5_; int n = j >> 8, k = j & 255; v = ldf(wdec, k * 128 + n, f32);
    } else {
        int j = i - R6_; int row = j / 96, k = j - row * 96;
        v = (k < DIN_) ? ldf(xin, row * DIN_ + k, f32) : 0.f;
    }
    dst[i] = __float2bfloat16(v);
}

// ---------------------------------------------------------------------------
// CSR build: XCD-region-partitioned histogram/scatter + 3-phase scan.
// ---------------------------------------------------------------------------
#define NBS ((NN + 255) / 256)       // 79 scan blocks
#define CHUNK 2048
#define NCH ((EE + CHUNK - 1) / CHUNK)   // 313 chunks

__global__ __launch_bounds__(256) void hist_kernel(const void* __restrict__ ei,
                                                   int* __restrict__ deg,
                                                   const int* __restrict__ flags)
{
    const int i64 = flags[1];
    int r = blockIdx.x & 7;
    int c = blockIdx.x >> 3;
    int base = c * CHUNK + threadIdx.x;
#pragma unroll
    for (int k = 0; k < CHUNK / 256; k++) {
        int e = base + k * 256;
        if (e < EE) {
            int d = i64 ? (int)((const long long*)ei)[EE + e] : ((const int*)ei)[EE + e];
            if (d / 2500 == r) atomicAdd(&deg[d], 1);
        }
    }
}

__global__ void scan1_kernel(const int* __restrict__ deg, int* __restrict__ bsum)
{
    int idx = blockIdx.x * 256 + threadIdx.x;
    int v = (idx < NN) ? deg[idx] : 0;
#pragma unroll
    for (int o = 32; o; o >>= 1) v += __shfl_down(v, o);
    __shared__ int s[4];
    if ((threadIdx.x & 63) == 0) s[threadIdx.x >> 6] = v;
    __syncthreads();
    if (threadIdx.x == 0) bsum[blockIdx.x] = s[0] + s[1] + s[2] + s[3];
}

__global__ void scan2_kernel(const int* __restrict__ bsum, int* __restrict__ boff,
                             int* __restrict__ off)
{
    __shared__ int s[128];
    int t = threadIdx.x;
    int v = (t < NBS) ? bsum[t] : 0;
    s[t] = v;
    __syncthreads();
    for (int st = 1; st < 128; st <<= 1) {
        int u = (t >= st) ? s[t - st] : 0;
        __syncthreads();
        s[t] += u;
        __syncthreads();
    }
    if (t < NBS) boff[t] = s[t] - v;   // exclusive
    if (t == 0) off[NN] = EE;
}

__global__ void scan3_kernel(const int* __restrict__ deg, const int* __restrict__ boff,
                             int* __restrict__ off, int* __restrict__ cur)
{
    __shared__ int s[256];
    int idx = blockIdx.x * 256 + threadIdx.x;
    int t = threadIdx.x;
    int v = (idx < NN) ? deg[idx] : 0;
    s[t] = v;
    __syncthreads();
    for (int st = 1; st < 256; st <<= 1) {
        int u = (t >= st) ? s[t - st] : 0;
        __syncthreads();
        s[t] += u;
        __syncthreads();
    }
    if (idx < NN) { int o = boff[blockIdx.x] + s[t] - v; off[idx] = o; cur[idx] = o; }
}

__global__ __launch_bounds__(256) void scatter_kernel(const void* __restrict__ ei,
                                                      int* __restrict__ cur,
                                                      int* __restrict__ csr,
                                                      const int* __restrict__ flags)
{
    const int i64 = flags[1];
    int r = blockIdx.x & 7;
    int c = blockIdx.x >> 3;
    int base = c * CHUNK + threadIdx.x;
#pragma unroll
    for (int k = 0; k < CHUNK / 256; k++) {
        int e = base + k * 256;
        if (e < EE) {
            int s, d;
            if (i64) { s = (int)((const long long*)ei)[e]; d = (int)((const long long*)ei)[EE + e]; }
            else     { s = ((const int*)ei)[e];            d = ((const int*)ei)[EE + e]; }
            if (d / 2500 == r) {
                int pos = atomicAdd(&cur[d], 1);
                csr[pos] = s;
            }
        }
    }
}

// ---------------------------------------------------------------------------
// MFMA GEMM (16x16x32 bf16): C[M,NC] = A @ W + bias.
// ---------------------------------------------------------------------------
template<int KP, int NC, int CG, int OUT_MODE>
__global__ __launch_bounds__(256) void mfma_gemm_kernel(
    const __hip_bfloat16* __restrict__ A,
    const __hip_bfloat16* __restrict__ WT,
    const void* __restrict__ bias,
    void* __restrict__ Cout, int out_off, const int* __restrict__ flags)
{
    const int f32 = flags[0];
    constexpr int MB = 16 * (4 / CG);
    constexpr int CT = NC / (16 * CG);
    int w = threadIdx.x >> 6, l = threadIdx.x & 63;
    int rt = w / CG, cg = w - rt * CG;
    int m0 = blockIdx.x * MB + rt * 16;
    int n0 = cg * (16 * CT);
    int l15 = l & 15, kq = (l >> 4) * 8;
    const __hip_bfloat16* arow = A + (size_t)(m0 + l15) * KP + kq;

    floatx4 acc[CT];
#pragma unroll
    for (int ct = 0; ct < CT; ct++) acc[ct] = (floatx4){0.f, 0.f, 0.f, 0.f};

    for (int kc = 0; kc < KP / 32; kc++) {
        short8 a = *(const short8*)(arow + kc * 32);
#pragma unroll
        for (int ct = 0; ct < CT; ct++) {
            const __hip_bfloat16* brow = WT + (size_t)(n0 + ct * 16 + l15) * KP + kq;
            short8 b = *(const short8*)(brow + kc * 32);
            acc[ct] = __builtin_amdgcn_mfma_f32_16x16x32_bf16(a, b, acc[ct], 0, 0, 0);
        }
    }

    int quad = l >> 4;
#pragma unroll
    for (int ct = 0; ct < CT; ct++) {
        int col = n0 + ct * 16 + l15;
        float bb = bias ? ldf(bias, col, f32) : 0.f;
#pragma unroll
        for (int r = 0; r < 4; r++) {
            int row = m0 + quad * 4 + r;
            float v = acc[ct][r] + bb;
            size_t o = (size_t)row * NC + col;
            if (OUT_MODE == 0)      ((float*)Cout)[o] = v;
            else if (OUT_MODE == 1) ((__hip_bfloat16*)Cout)[o] = __float2bfloat16(v);
            else                    stf(Cout, out_off + (int)o, v, f32);
        }
    }
}

// ---------------------------------------------------------------------------
// BatchNorm (training) on bf16 Y — two-phase, atomic-free
// ---------------------------------------------------------------------------
#define BNB 128

__global__ __launch_bounds__(256) void bn_part_kernel(const unsigned* __restrict__ Y1,
                                                      float* __restrict__ part)
{
    int c2 = threadIdx.x & 63;          // channel pair
    int rg = threadIdx.x >> 6;          // 4 row groups / block
    float s0 = 0.f, q0 = 0.f, s1 = 0.f, q1 = 0.f;
    for (int r = blockIdx.x * 4 + rg; r < NN; r += BNB * 4) {
        float2 v = bfp(Y1[r * 64 + c2]);
        s0 += v.x; q0 += v.x * v.x;
        s1 += v.y; q1 += v.y * v.y;
    }
    __shared__ float rs[4][128], rq[4][128];
    rs[rg][2 * c2] = s0; rs[rg][2 * c2 + 1] = s1;
    rq[rg][2 * c2] = q0; rq[rg][2 * c2 + 1] = q1;
    __syncthreads();
    int c = threadIdx.x;
    float v;
    if (c < 128) v = rs[0][c] + rs[1][c] + rs[2][c] + rs[3][c];
    else { int ch = c - 128; v = rq[0][ch] + rq[1][ch] + rq[2][ch] + rq[3][ch]; }
    part[blockIdx.x * 256 + c] = v;
}

__global__ __launch_bounds__(256) void bn_reduce_kernel(const float* __restrict__ part,
                                                        float* __restrict__ sums)
{
    int c = threadIdx.x;
    float v = 0.f;
    for (int b = 0; b < BNB; b += 4) {
        v += part[b * 256 + c] + part[(b + 1) * 256 + c]
           + part[(b + 2) * 256 + c] + part[(b + 3) * 256 + c];
    }
    sums[c] = v;
}

__global__ void bn_relu_kernel(const unsigned* __restrict__ Y1, unsigned* __restrict__ X1,
                               const float* __restrict__ sums, const float* __restrict__ sumsq,
                               const void* __restrict__ g, const void* __restrict__ be,
                               const int* __restrict__ flags)
{
    const int f32 = flags[0];
    int idx = blockIdx.x * blockDim.x + threadIdx.x;
    if (idx >= NN * 64) return;
    int c2 = idx & 63;
    int c0 = 2 * c2, c1 = c0 + 1;
    float2 v = bfp(Y1[idx]);
    float mean0 = sums[c0] * (1.f / NN), mean1 = sums[c1] * (1.f / NN);
    float var0  = sumsq[c0] * (1.f / NN) - mean0 * mean0;
    float var1  = sumsq[c1] * (1.f / NN) - mean1 * mean1;
    float o0 = (v.x - mean0) * rsqrtf(fmaxf(var0, 0.f) + BN_EPS) * ldf(g, c0, f32) + ldf(be, c0, f32);
    float o1 = (v.y - mean1) * rsqrtf(fmaxf(var1, 0.f) + BN_EPS) * ldf(g, c1, f32) + ldf(be, c1, f32);
    X1[idx] = f2bf(make_float2(o0 > 0.f ? o0 : 0.f, o1 > 0.f ? o1 : 0.f));
}

// ---------------------------------------------------------------------------
// GIN: H[d] = X[d] + sum_{s in N(d)} X[s]
// Half-wave per dst; 8-deep unrolled gather (8 loads in flight per lane).
// ---------------------------------------------------------------------------
__global__ __launch_bounds__(256) void gin_gather_kernel(
    const uint2* __restrict__ X2, uint2* __restrict__ H2,
    const int* __restrict__ off, const int* __restrict__ csr)
{
    int hw = (blockIdx.x * blockDim.x + threadIdx.x) >> 5;
    int l5 = threadIdx.x & 31;
    if (hw >= NN) return;
    int d = hw;
    uint2 w0 = X2[(size_t)d * 32 + l5];
    float4 acc = bf4(w0.x, w0.y);
    int b = off[d], e = off[d + 1];
    int i = b;
    for (; i + 8 <= e; i += 8) {
        uint2 a0 = X2[(size_t)csr[i]     * 32 + l5];
        uint2 a1 = X2[(size_t)csr[i + 1] * 32 + l5];
        uint2 a2 = X2[(size_t)csr[i + 2] * 32 + l5];
        uint2 a3 = X2[(size_t)csr[i + 3] * 32 + l5];
        uint2 a4 = X2[(size_t)csr[i + 4] * 32 + l5];
        uint2 a5 = X2[(size_t)csr[i + 5] * 32 + l5];
        uint2 a6 = X2[(size_t)csr[i + 6] * 32 + l5];
        uint2 a7 = X2[(size_t)csr[i + 7] * 32 + l5];
        float4 f0 = bf4(a0.x, a0.y), f1 = bf4(a1.x, a1.y);
        float4 f2 = bf4(a2.x, a2.y), f3 = bf4(a3.x, a3.y);
        float4 f4_ = bf4(a4.x, a4.y), f5 = bf4(a5.x, a5.y);
        float4 f6 = bf4(a6.x, a6.y), f7 = bf4(a7.x, a7.y);
        acc.x += (f0.x + f1.x) + (f2.x + f3.x) + (f4_.x + f5.x) + (f6.x + f7.x);
        acc.y += (f0.y + f1.y) + (f2.y + f3.y) + (f4_.y + f5.y) + (f6.y + f7.y);
        acc.z += (f0.z + f1.z) + (f2.z + f3.z) + (f4_.z + f5.z) + (f6.z + f7.z);
        acc.w += (f0.w + f1.w) + (f2.w + f3.w) + (f4_.w + f5.w) + (f6.w + f7.w);
    }
    for (; i < e; i++) {
        uint2 a = X2[(size_t)csr[i] * 32 + l5];
        float4 f = bf4(a.x, a.y);
        acc.x += f.x; acc.y += f.y; acc.z += f.z; acc.w += f.w;
    }
    H2[(size_t)d * 32 + l5] = f4bf(acc);
}

// ---------------------------------------------------------------------------
// VAE reparameterization; MULV: [N][256] bf16 (mu | logvar)
// ---------------------------------------------------------------------------
__global__ void z_kernel(const __hip_bfloat16* __restrict__ MULV, const void* __restrict__ eps,
                         const void* __restrict__ b_mu, const void* __restrict__ b_var,
                         __hip_bfloat16* __restrict__ Z, void* __restrict__ out,
                         const int* __restrict__ flags)
{
    const int f32 = flags[0];
    int idx = blockIdx.x * blockDim.x + threadIdx.x;
    if (idx >= NN * CC) return;
    int row = idx >> 7, c = idx & 127;
    float mu = b2f(MULV[row * 256 + c]) + ldf(b_mu, c, f32);
    float lv = b2f(MULV[row * 256 + 128 + c]) + ldf(b_var, c, f32);
    float z = ldf(eps, idx, f32) * expf(0.5f * lv) + mu;
    Z[idx] = __float2bfloat16(z);
    stf(out, idx, z, f32);                  // zin
    stf(out, 2 * NN * CC + idx, mu, f32);   // mu
    stf(out, 3 * NN * CC + idx, lv, f32);   // logvar
}

// ---------------------------------------------------------------------------
// GAT attention scores per (node, head), bf16 HH
// ---------------------------------------------------------------------------
__global__ void att_kernel(const __hip_bfloat16* __restrict__ HHb,
                           const void* __restrict__ att_src, const void* __restrict__ att_dst,
                           float* __restrict__ AS, float* __restrict__ AD,
                           const int* __restrict__ flags)
{
    const int f32 = flags[0];
    int wid  = (blockIdx.x * blockDim.x + threadIdx.x) >> 6;
    int lane = threadIdx.x & 63;
    if (wid >= NN * 2) return;
    int n = wid >> 1, h = wid & 1;
    int base = n * 256 + h * CC;
    float v1 = b2f(HHb[base + lane]), v2 = b2f(HHb[base + lane + 64]);
    float s = v1 * ldf(att_src, h * CC + lane, f32) + v2 * ldf(att_src, h * CC + lane + 64, f32);
    float d = v1 * ldf(att_dst, h * CC + lane, f32) + v2 * ldf(att_dst, h * CC + lane + 64, f32);
#pragma unroll
    for (int off = 32; off; off >>= 1) {
        s += __shfl_down(s, off);
        d += __shfl_down(d, off);
    }
    if (lane == 0) { AS[wid] = s; AD[wid] = d; }
}

// ---------------------------------------------------------------------------
// GAT softmax stats per (node, head) + alpha materialization
// ---------------------------------------------------------------------------
__global__ void gat_stats_kernel(const float* __restrict__ AS, const float* __restrict__ AD,
                                 const int* __restrict__ off, const int* __restrict__ csr,
                                 float* __restrict__ ALPHA, float* __restrict__ SALPHA)
{
    int wid  = (blockIdx.x * blockDim.x + threadIdx.x) >> 6;
    int lane = threadIdx.x & 63;
    if (wid >= NN * 2) return;
    int n = wid >> 1, h = wid & 1;
    int b = off[n], e = off[n + 1];
    float adh = AD[n * 2 + h];
    float self_l = leaky02(AS[n * 2 + h] + adh);
    float m = (lane == 0) ? self_l : NEG_INF;
    for (int i = b + lane; i < e; i += 64) {
        int s = csr[i];
        m = fmaxf(m, leaky02(AS[s * 2 + h] + adh));
    }
#pragma unroll
    for (int o = 32; o; o >>= 1) m = fmaxf(m, __shfl_xor(m, o));
    float sum = (lane == 0) ? expf(self_l - m) : 0.f;
    for (int i = b + lane; i < e; i += 64) {
        int s = csr[i];
        sum += expf(leaky02(AS[s * 2 + h] + adh) - m);
    }
#pragma unroll
    for (int o = 32; o; o >>= 1) sum += __shfl_xor(sum, o);
    float inv = 1.f / sum;
    for (int i = b + lane; i < e; i += 64) {
        int s = csr[i];
        ALPHA[i * 2 + h] = expf(leaky02(AS[s * 2 + h] + adh) - m) * inv;
    }
    if (lane == 0) SALPHA[wid] = expf(self_l - m) * inv;
}

// ---------------------------------------------------------------------------
// GAT aggregation, half-wave per dst: 32 lanes x uint4 = 512 B row;
// alpha pre-materialized; 8-deep unroll (8 gathers in flight per lane);
// OUT += b_gat fused.
// ---------------------------------------------------------------------------
__global__ __launch_bounds__(256) void gat_agg_kernel(
    const uint4* __restrict__ HH4,
    const float* __restrict__ ALPHA, const float* __restrict__ SALPHA,
    const int* __restrict__ off, const int* __restrict__ csr,
    const void* __restrict__ b_gat, uint4* __restrict__ OUT4,
    const int* __restrict__ flags)
{
    const int f32 = flags[0];
    int hw = (blockIdx.x * blockDim.x + threadIdx.x) >> 5;
    int l5 = threadIdx.x & 31;
    if (hw >= NN) return;
    int d = hw, h = l5 >> 4;
    uint4 wv = HH4[(size_t)d * 32 + l5];
    float a0 = SALPHA[d * 2 + h];
    float4 p = bf4(wv.x, wv.y), q = bf4(wv.z, wv.w);
    float4 accA = make_float4(a0 * p.x, a0 * p.y, a0 * p.z, a0 * p.w);
    float4 accB = make_float4(a0 * q.x, a0 * q.y, a0 * q.z, a0 * q.w);
    int b = off[d], e = off[d + 1];
    int i = b;
    for (; i + 8 <= e; i += 8) {
        uint4 w0 = HH4[(size_t)csr[i]     * 32 + l5];
        uint4 w1 = HH4[(size_t)csr[i + 1] * 32 + l5];
        uint4 w2 = HH4[(size_t)csr[i + 2] * 32 + l5];
        uint4 w3 = HH4[(size_t)csr[i + 3] * 32 + l5];
        uint4 w4 = HH4[(size_t)csr[i + 4] * 32 + l5];
        uint4 w5 = HH4[(size_t)csr[i + 5] * 32 + l5];
        uint4 w6 = HH4[(size_t)csr[i + 6] * 32 + l5];
        uint4 w7 = HH4[(size_t)csr[i + 7] * 32 + l5];
        float a1 = ALPHA[(i)     * 2 + h];
        float a2 = ALPHA[(i + 1) * 2 + h];
        float a3 = ALPHA[(i + 2) * 2 + h];
        float a4 = ALPHA[(i + 3) * 2 + h];
        float a5 = ALPHA[(i + 4) * 2 + h];
        float a6 = ALPHA[(i + 5) * 2 + h];
        float a7 = ALPHA[(i + 6) * 2 + h];
        float a8 = ALPHA[(i + 7) * 2 + h];
        float4 f;
        f = bf4(w0.x, w0.y); accA.x += a1 * f.x; accA.y += a1 * f.y; accA.z += a1 * f.z; accA.w += a1 * f.w;
        f = bf4(w0.z, w0.w); accB.x += a1 * f.x; accB.y += a1 * f.y; accB.z += a1 * f.z; accB.w += a1 * f.w;
        f = bf4(w1.x, w1.y); accA.x += a2 * f.x; accA.y += a2 * f.y; accA.z += a2 * f.z; accA.w += a2 * f.w;
        f = bf4(w1.z, w1.w); accB.x += a2 * f.x; accB.y += a2 * f.y; accB.z += a2 * f.z; accB.w += a2 * f.w;
        f = bf4(w2.x, w2.y); accA.x += a3 * f.x; accA.y += a3 * f.y; accA.z += a3 * f.z; accA.w += a3 * f.w;
        f = bf4(w2.z, w2.w); accB.x += a3 * f.x; accB.y += a3 * f.y; accB.z += a3 * f.z; accB.w += a3 * f.w;
        f = bf4(w3.x, w3.y); accA.x += a4 * f.x; accA.y += a4 * f.y; accA.z += a4 * f.z; accA.w += a4 * f.w;
        f = bf4(w3.z, w3.w); accB.x += a4 * f.x; accB.y += a4 * f.y; accB.z += a4 * f.z; accB.w += a4 * f.w;
        f = bf4(w4.x, w4.y); accA.x += a5 * f.x; accA.y += a5 * f.y; accA.z += a5 * f.z; accA.w += a5 * f.w;
        f = bf4(w4.z, w4.w); accB.x += a5 * f.x; accB.y += a5 * f.y; accB.z += a5 * f.z; accB.w += a5 * f.w;
        f = bf4(w5.x, w5.y); accA.x += a6 * f.x; accA.y += a6 * f.y; accA.z += a6 * f.z; accA.w += a6 * f.w;
        f = bf4(w5.z, w5.w); accB.x += a6 * f.x; accB.y += a6 * f.y; accB.z += a6 * f.z; accB.w += a6 * f.w;
        f = bf4(w6.x, w6.y); accA.x += a7 * f.x; accA.y += a7 * f.y; accA.z += a7 * f.z; accA.w += a7 * f.w;
        f = bf4(w6.z, w6.w); accB.x += a7 * f.x; accB.y += a7 * f.y; accB.z += a7 * f.z; accB.w += a7 * f.w;
        f = bf4(w7.x, w7.y); accA.x += a8 * f.x; accA.y += a8 * f.y; accA.z += a8 * f.z; accA.w += a8 * f.w;
        f = bf4(w7.z, w7.w); accB.x += a8 * f.x; accB.y += a8 * f.y; accB.z += a8 * f.z; accB.w += a8 * f.w;
    }
    for (; i < e; i++) {
        uint4 w = HH4[(size_t)csr[i] * 32 + l5];
        float al = ALPHA[i * 2 + h];
        float4 f = bf4(w.x, w.y);
        accA.x += al * f.x; accA.y += al * f.y; accA.z += al * f.z; accA.w += al * f.w;
        f = bf4(w.z, w.w);
        accB.x += al * f.x; accB.y += al * f.y; accB.z += al * f.z; accB.w += al * f.w;
    }
    int c0 = 8 * l5;
    accA.x += ldf(b_gat, c0 + 0, f32); accA.y += ldf(b_gat, c0 + 1, f32);
    accA.z += ldf(b_gat, c0 + 2, f32); accA.w += ldf(b_gat, c0 + 3, f32);
    accB.x += ldf(b_gat, c0 + 4, f32); accB.y += ldf(b_gat, c0 + 5, f32);
    accB.z += ldf(b_gat, c0 + 6, f32); accB.w += ldf(b_gat, c0 + 7, f32);
    uint2 oa = f4bf(accA), ob = f4bf(accB);
    uint4 o; o.x = oa.x; o.y = oa.y; o.z = ob.x; o.w = ob.y;
    OUT4[(size_t)d * 32 + l5] = o;
}

// ---------------------------------------------------------------------------
extern "C" void kernel_launch(void* const* d_in, const int* in_sizes, int n_in,
                              void* d_out, int out_size, void* d_ws, size_t ws_size,
                              hipStream_t stream)
{
    const void* xin    = d_in[0];
    const void* ei     = d_in[1];
    const void* eps    = d_in[2];
    const void* W_emb  = d_in[3];
    const void* b_emb  = d_in[4];
    const void* g_emb  = d_in[5];
    const void* be_emb = d_in[6];
    const void* W1     = d_in[7];
    const void* b1     = d_in[8];
    const void* g1     = d_in[9];
    const void* be1    = d_in[10];
    const void* W2     = d_in[11];
    const void* b2     = d_in[12];
    const void* W_mu   = d_in[13];
    const void* b_mu   = d_in[14];
    const void* W_var  = d_in[15];
    const void* b_var  = d_in[16];
    const void* W_gat  = d_in[17];
    const void* attS   = d_in[18];
    const void* attD   = d_in[19];
    const void* b_gat  = d_in[20];
    const void* W_dec  = d_in[21];
    const void* b_dec  = d_in[22];

    // workspace layout: 4*NB fp32 slots + tail ≈ 53.8 MB
    float* ws = (float*)d_ws;
    const size_t NB = (size_t)NN * CC;       // 2,560,000
    float* B0 = ws;                          // bf16 MULV (N x 256) | bf16 HH
    float* B1 = ws + 1 * NB;                 // bf16 Y | bf16 OUT (N x 256)
    float* B2 = ws + 2 * NB;                 // bf16 Xbf | Hbf
    float* B3 = ws + 3 * NB;                 // bf16 Zbf | Zobf
    __hip_bfloat16* Xbf   = (__hip_bfloat16*)B2;       // N x 128
    __hip_bfloat16* Hbf   = Xbf + NB;                  // N x 128
    __hip_bfloat16* Zbf   = (__hip_bfloat16*)B3;       // N x 128
    __hip_bfloat16* Zobf  = Zbf + NB;                  // N x 128
    __hip_bfloat16* HHbf  = (__hip_bfloat16*)B0;       // N x 256
    __hip_bfloat16* OUTbf = (__hip_bfloat16*)B1;       // N x 256
    __hip_bfloat16* Ybf   = (__hip_bfloat16*)B1;       // N x 128 (BN input)
    __hip_bfloat16* MULV  = (__hip_bfloat16*)B0;       // N x 256 (mu|logvar)
    float* TAIL  = ws + 4 * NB;
    float* AS     = TAIL;                    // 40000
    float* AD     = TAIL + 40000;            // 40000
    float* SALPHA = TAIL + 80000;            // 40000
    int*   FLAGS  = (int*)(TAIL + 120000);   // 16
    int*   BSUM   = FLAGS + 16;              // 128
    int*   BOFF   = BSUM + 128;              // 128
    int*   DEG    = BOFF + 128;              // 20000  <- zeroed
    float* SUMS   = (float*)(DEG + 20000);   // 256 (sums | sumsq)
    float* PART   = SUMS + 256;              // BNB*256 = 32768
    int*   OFF    = (int*)(PART + BNB * 256); // 20008 (padded)
    int*   CUR    = OFF + 20008;             // 20000
    int*   CSR    = CUR + 20000;             // 640000
    float* ALPHA  = (float*)(CSR + 640000);  // 1,280,000
    __hip_bfloat16* WTB = (__hip_bfloat16*)(ALPHA + 1280000);  // 143360 bf16
    __hip_bfloat16* WTemb = WTB;
    __hip_bfloat16* WT1   = WTB + R0_;
    __hip_bfloat16* WT2   = WTB + R1_;
    __hip_bfloat16* WTmuv = WTB + R2_;       // mu|var contiguous -> NC=256
    __hip_bfloat16* WTgat = WTB + R4_;
    __hip_bfloat16* WTdec = WTB + R5_;
    __hip_bfloat16* Xin   = WTB + R6_;       // NN x 96 bf16

    detect_kernel<<<1, 256, 0, stream>>>((const unsigned int*)xin,
                                         (const unsigned int*)ei, FLAGS);

    // -------- merged weight transpose + node-feature conversion --------
    cvt_all_kernel<<<(TCVT + 255) / 256, 256, 0, stream>>>(
        W_emb, W1, W2, W_mu, W_var, W_gat, W_dec, xin, WTB, FLAGS);

    // -------- memset: DEG only --------
    hipMemsetAsync(DEG, 0, 20000 * sizeof(int), stream);

    // -------- CSR build (sorted by destination, XCD-region partitioned) ------
    hist_kernel<<<NCH * 8, 256, 0, stream>>>(ei, DEG, FLAGS);
    scan1_kernel<<<NBS, 256, 0, stream>>>(DEG, BSUM);
    scan2_kernel<<<1, 128, 0, stream>>>(BSUM, BOFF, OFF);
    scan3_kernel<<<NBS, 256, 0, stream>>>(DEG, BOFF, OFF, CUR);
    scatter_kernel<<<NCH * 8, 256, 0, stream>>>(ei, CUR, CSR, FLAGS);

    // -------- Stage A: atom embedding = relu(BN(x @ W_emb + b_emb)) -> Xbf ----
    mfma_gemm_kernel<96, 128, 2, 1><<<NN / 32, 256, 0, stream>>>(
        Xin, WTemb, b_emb, Ybf, 0, FLAGS);
    bn_part_kernel<<<BNB, 256, 0, stream>>>((const unsigned*)Ybf, PART);
    bn_reduce_kernel<<<1, 256, 0, stream>>>(PART, SUMS);
    bn_relu_kernel<<<(NN * 64) / 256, 256, 0, stream>>>(
        (const unsigned*)Ybf, (unsigned*)Xbf, SUMS, SUMS + 128, g_emb, be_emb, FLAGS);

    // -------- Stage B: GIN x2: x = W2( relu(BN(W1(x+agg))) ) --------
    for (int t = 0; t < 2; t++) {
        gin_gather_kernel<<<NN / 8, 256, 0, stream>>>(
            (const uint2*)Xbf, (uint2*)Hbf, OFF, CSR);
        mfma_gemm_kernel<128, 128, 2, 1><<<NN / 32, 256, 0, stream>>>(
            Hbf, WT1, b1, Ybf, 0, FLAGS);
        bn_part_kernel<<<BNB, 256, 0, stream>>>((const unsigned*)Ybf, PART);
        bn_reduce_kernel<<<1, 256, 0, stream>>>(PART, SUMS);
        bn_relu_kernel<<<(NN * 64) / 256, 256, 0, stream>>>(
            (const unsigned*)Ybf, (unsigned*)Hbf, SUMS, SUMS + 128, g1, be1, FLAGS);
        mfma_gemm_kernel<128, 128, 2, 1><<<NN / 32, 256, 0, stream>>>(
            Hbf, WT2, b2, Xbf, 0, FLAGS);
    }

    // -------- Stage C: merged VAE heads (Xbf -> MULV bf16 N x 256) --------
    mfma_gemm_kernel<128, 256, 4, 1><<<NN / 16, 256, 0, stream>>>(
        Xbf, WTmuv, nullptr, MULV, 0, FLAGS);
    z_kernel<<<(NN * CC) / 256, 256, 0, stream>>>(MULV, eps, b_mu, b_var, Zbf, d_out, FLAGS);

    // -------- Stage D: GAT x2; decoder as MFMA GEMM --------
    const __hip_bfloat16* zc = Zbf;
    for (int t = 0; t < 2; t++) {
        mfma_gemm_kernel<128, 256, 4, 1><<<NN / 16, 256, 0, stream>>>(
            zc, WTgat, nullptr, HHbf, 0, FLAGS);
        att_kernel<<<(NN * 2) / 4, 256, 0, stream>>>(HHbf, attS, attD, AS, AD, FLAGS);
        gat_stats_kernel<<<(NN * 2) / 4, 256, 0, stream>>>(AS, AD, OFF, CSR, ALPHA, SALPHA);
        gat_agg_kernel<<<NN / 8, 256, 0, stream>>>(
            (const uint4*)HHbf, ALPHA, SALPHA, OFF, CSR, b_gat, (uint4*)OUTbf, FLAGS);
        if (t == 0) {
            mfma_gemm_kernel<256, 128, 2, 1><<<NN / 32, 256, 0, stream>>>(
                OUTbf, WTdec, b_dec, Zobf, 0, FLAGS);
            zc = Zobf;
        } else {
            mfma_gemm_kernel<256, 128, 2, 2><<<NN / 32, 256, 0, stream>>>(
                OUTbf, WTdec, b_dec, d_out, NN * CC, FLAGS);
        }
    }
}

// Round 13
// 592.041 us; speedup vs baseline: 1.0087x; 1.0087x over previous
//
#include <hip/hip_runtime.h>
#include <hip/hip_bf16.h>

// Problem constants
#define NN   20000          // nodes
#define DIN_ 92             // atom feature dim
#define CC   128            // hidden dim
#define EE   640000         // edges (self loops handled explicitly)
#define BN_EPS 1e-5f
#define NEG_INF (-3.0e38f)

typedef short short8 __attribute__((ext_vector_type(8)));
typedef float floatx4 __attribute__((ext_vector_type(4)));

// ---------------------------------------------------------------------------
// Dual-dtype helpers: flags[0]=1 -> external floats are fp32 (else bf16)
//                     flags[1]=1 -> edge_index is int64 (else int32)
// ---------------------------------------------------------------------------
static __device__ __forceinline__ float b2f(__hip_bfloat16 v) { return __bfloat162float(v); }
static __device__ __forceinline__ float ldf(const void* p, int i, int f32) {
    return f32 ? ((const float*)p)[i]
               : __bfloat162float(((const __hip_bfloat16*)p)[i]);
}
static __device__ __forceinline__ void stf(void* p, int i, float v, int f32) {
    if (f32) ((float*)p)[i] = v;
    else     ((__hip_bfloat16*)p)[i] = __float2bfloat16(v);
}
static __device__ __forceinline__ float leaky02(float x) { return x > 0.f ? x : 0.2f * x; }

// bf16 decode via bit ops (bf16 = top half of fp32)
static __device__ __forceinline__ float2 bfp(unsigned w) {
    return make_float2(__uint_as_float(w << 16), __uint_as_float(w & 0xffff0000u));
}
static __device__ __forceinline__ float4 bf4(unsigned x, unsigned y) {
    return make_float4(__uint_as_float(x << 16), __uint_as_float(x & 0xffff0000u),
                       __uint_as_float(y << 16), __uint_as_float(y & 0xffff0000u));
}
static __device__ __forceinline__ uint2 f4bf(float4 v) {
    union { uint2 u; __hip_bfloat16 b[4]; } x;
    x.b[0] = __float2bfloat16(v.x); x.b[1] = __float2bfloat16(v.y);
    x.b[2] = __float2bfloat16(v.z); x.b[3] = __float2bfloat16(v.w);
    return x.u;
}
static __device__ __forceinline__ unsigned f2bf(float2 v) {
    union { unsigned u; __hip_bfloat16 b[2]; } x;
    x.b[0] = __float2bfloat16(v.x); x.b[1] = __float2bfloat16(v.y);
    return x.u;
}

// ---------------------------------------------------------------------------
// Runtime dtype detection
// ---------------------------------------------------------------------------
__global__ void detect_kernel(const unsigned int* __restrict__ x0,
                              const unsigned int* __restrict__ ei,
                              int* __restrict__ flags)
{
    __shared__ int cnt_band, cnt_zero;
    if (threadIdx.x == 0) { cnt_band = 0; cnt_zero = 0; }
    __syncthreads();
    unsigned w  = x0[threadIdx.x];
    unsigned eb = ((w & 0xFFFFu) >> 7) & 0xFFu;
    if (eb >= 90u && eb <= 140u) atomicAdd(&cnt_band, 1);
    if (ei[2 * threadIdx.x + 1] == 0u) atomicAdd(&cnt_zero, 1);
    __syncthreads();
    if (threadIdx.x == 0) {
        flags[0] = (cnt_band < 200) ? 1 : 0;   // 1 = fp32
        flags[1] = (cnt_zero >= 250) ? 1 : 0;  // 1 = int64
    }
}

// ---------------------------------------------------------------------------
// Merged conversion: transposed bf16 weights + padded bf16 node features
// ---------------------------------------------------------------------------
#define R0_ 12288
#define R1_ (R0_ + 16384)
#define R2_ (R1_ + 16384)
#define R3_ (R2_ + 16384)
#define R4_ (R3_ + 16384)
#define R5_ (R4_ + 32768)
#define R6_ (R5_ + 32768)          // 143360 weight elements
#define TCVT (R6_ + NN * 96)       // + node features

__global__ void cvt_all_kernel(const void* __restrict__ w_emb, const void* __restrict__ w1,
                               const void* __restrict__ w2, const void* __restrict__ wmu,
                               const void* __restrict__ wvar, const void* __restrict__ wgat,
                               const void* __restrict__ wdec, const void* __restrict__ xin,
                               __hip_bfloat16* __restrict__ dst, const int* __restrict__ flags)
{
    const int f32 = flags[0];
    int i = blockIdx.x * blockDim.x + threadIdx.x;
    if (i >= TCVT) return;
    float v;
    if (i < R0_) {
        int n = i / 96, k = i - n * 96;
        v = (k < DIN_) ? ldf(w_emb, k * 128 + n, f32) : 0.f;
    } else if (i < R1_) {
        int j = i - R0_; int n = j >> 7, k = j & 127; v = ldf(w1, k * 128 + n, f32);
    } else if (i < R2_) {
        int j = i - R1_; int n = j >> 7, k = j & 127; v = ldf(w2, k * 128 + n, f32);
    } else if (i < R3_) {
        int j = i - R2_; int n = j >> 7, k = j & 127; v = ldf(wmu, k * 128 + n, f32);
    } else if (i < R4_) {
        int j = i - R3_; int n = j >> 7, k = j & 127; v = ldf(wvar, k * 128 + n, f32);
    } else if (i < R5_) {
        int j = i - R4_; int n = j >> 7, k = j & 127; v = ldf(wgat, k * 256 + n, f32);
    } else if (i < R6_) {
        int j = i - R5_; int n = j >> 8, k = j & 255; v = ldf(wdec, k * 128 + n, f32);
    } else {
        int j = i - R6_; int row = j / 96, k = j - row * 96;
        v = (k < DIN_) ? ldf(xin, row * DIN_ + k, f32) : 0.f;
    }
    dst[i] = __float2bfloat16(v);
}

// ---------------------------------------------------------------------------
// CSR build: XCD-region-partitioned histogram/scatter + 3-phase scan.
// ---------------------------------------------------------------------------
#define NBS ((NN + 255) / 256)       // 79 scan blocks
#define CHUNK 2048
#define NCH ((EE + CHUNK - 1) / CHUNK)   // 313 chunks

__global__ __launch_bounds__(256) void hist_kernel(const void* __restrict__ ei,
                                                   int* __restrict__ deg,
                                                   const int* __restrict__ flags)
{
    const int i64 = flags[1];
    int r = blockIdx.x & 7;
    int c = blockIdx.x >> 3;
    int base = c * CHUNK + threadIdx.x;
#pragma unroll
    for (int k = 0; k < CHUNK / 256; k++) {
        int e = base + k * 256;
        if (e < EE) {
            int d = i64 ? (int)((const long long*)ei)[EE + e] : ((const int*)ei)[EE + e];
            if (d / 2500 == r) atomicAdd(&deg[d], 1);
        }
    }
}

__global__ void scan1_kernel(const int* __restrict__ deg, int* __restrict__ bsum)
{
    int idx = blockIdx.x * 256 + threadIdx.x;
    int v = (idx < NN) ? deg[idx] : 0;
#pragma unroll
    for (int o = 32; o; o >>= 1) v += __shfl_down(v, o);
    __shared__ int s[4];
    if ((threadIdx.x & 63) == 0) s[threadIdx.x >> 6] = v;
    __syncthreads();
    if (threadIdx.x == 0) bsum[blockIdx.x] = s[0] + s[1] + s[2] + s[3];
}

__global__ void scan2_kernel(const int* __restrict__ bsum, int* __restrict__ boff,
                             int* __restrict__ off)
{
    __shared__ int s[128];
    int t = threadIdx.x;
    int v = (t < NBS) ? bsum[t] : 0;
    s[t] = v;
    __syncthreads();
    for (int st = 1; st < 128; st <<= 1) {
        int u = (t >= st) ? s[t - st] : 0;
        __syncthreads();
        s[t] += u;
        __syncthreads();
    }
    if (t < NBS) boff[t] = s[t] - v;   // exclusive
    if (t == 0) off[NN] = EE;
}

__global__ void scan3_kernel(const int* __restrict__ deg, const int* __restrict__ boff,
                             int* __restrict__ off, int* __restrict__ cur)
{
    __shared__ int s[256];
    int idx = blockIdx.x * 256 + threadIdx.x;
    int t = threadIdx.x;
    int v = (idx < NN) ? deg[idx] : 0;
    s[t] = v;
    __syncthreads();
    for (int st = 1; st < 256; st <<= 1) {
        int u = (t >= st) ? s[t - st] : 0;
        __syncthreads();
        s[t] += u;
        __syncthreads();
    }
    if (idx < NN) { int o = boff[blockIdx.x] + s[t] - v; off[idx] = o; cur[idx] = o; }
}

__global__ __launch_bounds__(256) void scatter_kernel(const void* __restrict__ ei,
                                                      int* __restrict__ cur,
                                                      int* __restrict__ csr,
                                                      const int* __restrict__ flags)
{
    const int i64 = flags[1];
    int r = blockIdx.x & 7;
    int c = blockIdx.x >> 3;
    int base = c * CHUNK + threadIdx.x;
#pragma unroll
    for (int k = 0; k < CHUNK / 256; k++) {
        int e = base + k * 256;
        if (e < EE) {
            int s, d;
            if (i64) { s = (int)((const long long*)ei)[e]; d = (int)((const long long*)ei)[EE + e]; }
            else     { s = ((const int*)ei)[e];            d = ((const int*)ei)[EE + e]; }
            if (d / 2500 == r) {
                int pos = atomicAdd(&cur[d], 1);
                csr[pos] = s;
            }
        }
    }
}

// ---------------------------------------------------------------------------
// MFMA GEMM (16x16x32 bf16): C[M,NC] = A @ W + bias.
// ---------------------------------------------------------------------------
template<int KP, int NC, int CG, int OUT_MODE>
__global__ __launch_bounds__(256) void mfma_gemm_kernel(
    const __hip_bfloat16* __restrict__ A,
    const __hip_bfloat16* __restrict__ WT,
    const void* __restrict__ bias,
    void* __restrict__ Cout, int out_off, const int* __restrict__ flags)
{
    const int f32 = flags[0];
    constexpr int MB = 16 * (4 / CG);
    constexpr int CT = NC / (16 * CG);
    int w = threadIdx.x >> 6, l = threadIdx.x & 63;
    int rt = w / CG, cg = w - rt * CG;
    int m0 = blockIdx.x * MB + rt * 16;
    int n0 = cg * (16 * CT);
    int l15 = l & 15, kq = (l >> 4) * 8;
    const __hip_bfloat16* arow = A + (size_t)(m0 + l15) * KP + kq;

    floatx4 acc[CT];
#pragma unroll
    for (int ct = 0; ct < CT; ct++) acc[ct] = (floatx4){0.f, 0.f, 0.f, 0.f};

    for (int kc = 0; kc < KP / 32; kc++) {
        short8 a = *(const short8*)(arow + kc * 32);
#pragma unroll
        for (int ct = 0; ct < CT; ct++) {
            const __hip_bfloat16* brow = WT + (size_t)(n0 + ct * 16 + l15) * KP + kq;
            short8 b = *(const short8*)(brow + kc * 32);
            acc[ct] = __builtin_amdgcn_mfma_f32_16x16x32_bf16(a, b, acc[ct], 0, 0, 0);
        }
    }

    int quad = l >> 4;
#pragma unroll
    for (int ct = 0; ct < CT; ct++) {
        int col = n0 + ct * 16 + l15;
        float bb = bias ? ldf(bias, col, f32) : 0.f;
#pragma unroll
        for (int r = 0; r < 4; r++) {
            int row = m0 + quad * 4 + r;
            float v = acc[ct][r] + bb;
            size_t o = (size_t)row * NC + col;
            if (OUT_MODE == 0)      ((float*)Cout)[o] = v;
            else if (OUT_MODE == 1) ((__hip_bfloat16*)Cout)[o] = __float2bfloat16(v);
            else                    stf(Cout, out_off + (int)o, v, f32);
        }
    }
}

// ---------------------------------------------------------------------------
// BatchNorm (training) on bf16 Y — two-phase, atomic-free
// ---------------------------------------------------------------------------
#define BNB 128

__global__ __launch_bounds__(256) void bn_part_kernel(const unsigned* __restrict__ Y1,
                                                      float* __restrict__ part)
{
    int c2 = threadIdx.x & 63;          // channel pair
    int rg = threadIdx.x >> 6;          // 4 row groups / block
    float s0 = 0.f, q0 = 0.f, s1 = 0.f, q1 = 0.f;
    for (int r = blockIdx.x * 4 + rg; r < NN; r += BNB * 4) {
        float2 v = bfp(Y1[r * 64 + c2]);
        s0 += v.x; q0 += v.x * v.x;
        s1 += v.y; q1 += v.y * v.y;
    }
    __shared__ float rs[4][128], rq[4][128];
    rs[rg][2 * c2] = s0; rs[rg][2 * c2 + 1] = s1;
    rq[rg][2 * c2] = q0; rq[rg][2 * c2 + 1] = q1;
    __syncthreads();
    int c = threadIdx.x;
    float v;
    if (c < 128) v = rs[0][c] + rs[1][c] + rs[2][c] + rs[3][c];
    else { int ch = c - 128; v = rq[0][ch] + rq[1][ch] + rq[2][ch] + rq[3][ch]; }
    part[blockIdx.x * 256 + c] = v;
}

__global__ __launch_bounds__(256) void bn_reduce_kernel(const float* __restrict__ part,
                                                        float* __restrict__ sums)
{
    int c = threadIdx.x;
    float v = 0.f;
    for (int b = 0; b < BNB; b += 4) {
        v += part[b * 256 + c] + part[(b + 1) * 256 + c]
           + part[(b + 2) * 256 + c] + part[(b + 3) * 256 + c];
    }
    sums[c] = v;
}

__global__ void bn_relu_kernel(const unsigned* __restrict__ Y1, unsigned* __restrict__ X1,
                               const float* __restrict__ sums, const float* __restrict__ sumsq,
                               const void* __restrict__ g, const void* __restrict__ be,
                               const int* __restrict__ flags)
{
    const int f32 = flags[0];
    int idx = blockIdx.x * blockDim.x + threadIdx.x;
    if (idx >= NN * 64) return;
    int c2 = idx & 63;
    int c0 = 2 * c2, c1 = c0 + 1;
    float2 v = bfp(Y1[idx]);
    float mean0 = sums[c0] * (1.f / NN), mean1 = sums[c1] * (1.f / NN);
    float var0  = sumsq[c0] * (1.f / NN) - mean0 * mean0;
    float var1  = sumsq[c1] * (1.f / NN) - mean1 * mean1;
    float o0 = (v.x - mean0) * rsqrtf(fmaxf(var0, 0.f) + BN_EPS) * ldf(g, c0, f32) + ldf(be, c0, f32);
    float o1 = (v.y - mean1) * rsqrtf(fmaxf(var1, 0.f) + BN_EPS) * ldf(g, c1, f32) + ldf(be, c1, f32);
    X1[idx] = f2bf(make_float2(o0 > 0.f ? o0 : 0.f, o1 > 0.f ? o1 : 0.f));
}

// ---------------------------------------------------------------------------
// GIN: H[d] = X[d] + sum_{s in N(d)} X[s]
// Half-wave per dst: 32 lanes x uint2 (8 B) = full 256 B bf16 row. 4-deep.
// (8-deep regressed: VGPR 32->56, occupancy 55->30% — r12 post-mortem)
// ---------------------------------------------------------------------------
__global__ __launch_bounds__(256) void gin_gather_kernel(
    const uint2* __restrict__ X2, uint2* __restrict__ H2,
    const int* __restrict__ off, const int* __restrict__ csr)
{
    int hw = (blockIdx.x * blockDim.x + threadIdx.x) >> 5;
    int l5 = threadIdx.x & 31;
    if (hw >= NN) return;
    int d = hw;
    uint2 w0 = X2[(size_t)d * 32 + l5];
    float4 acc = bf4(w0.x, w0.y);
    int b = off[d], e = off[d + 1];
    int i = b;
    for (; i + 4 <= e; i += 4) {
        int s0 = csr[i], s1 = csr[i + 1], s2 = csr[i + 2], s3 = csr[i + 3];
        uint2 a0 = X2[(size_t)s0 * 32 + l5];
        uint2 a1 = X2[(size_t)s1 * 32 + l5];
        uint2 a2 = X2[(size_t)s2 * 32 + l5];
        uint2 a3 = X2[(size_t)s3 * 32 + l5];
        float4 f0 = bf4(a0.x, a0.y), f1 = bf4(a1.x, a1.y);
        float4 f2 = bf4(a2.x, a2.y), f3 = bf4(a3.x, a3.y);
        acc.x += f0.x + f1.x + f2.x + f3.x;
        acc.y += f0.y + f1.y + f2.y + f3.y;
        acc.z += f0.z + f1.z + f2.z + f3.z;
        acc.w += f0.w + f1.w + f2.w + f3.w;
    }
    for (; i < e; i++) {
        uint2 a = X2[(size_t)csr[i] * 32 + l5];
        float4 f = bf4(a.x, a.y);
        acc.x += f.x; acc.y += f.y; acc.z += f.z; acc.w += f.w;
    }
    H2[(size_t)d * 32 + l5] = f4bf(acc);
}

// ---------------------------------------------------------------------------
// VAE reparameterization; MULV: [N][256] bf16 (mu | logvar)
// ---------------------------------------------------------------------------
__global__ void z_kernel(const __hip_bfloat16* __restrict__ MULV, const void* __restrict__ eps,
                         const void* __restrict__ b_mu, const void* __restrict__ b_var,
                         __hip_bfloat16* __restrict__ Z, void* __restrict__ out,
                         const int* __restrict__ flags)
{
    const int f32 = flags[0];
    int idx = blockIdx.x * blockDim.x + threadIdx.x;
    if (idx >= NN * CC) return;
    int row = idx >> 7, c = idx & 127;
    float mu = b2f(MULV[row * 256 + c]) + ldf(b_mu, c, f32);
    float lv = b2f(MULV[row * 256 + 128 + c]) + ldf(b_var, c, f32);
    float z = ldf(eps, idx, f32) * expf(0.5f * lv) + mu;
    Z[idx] = __float2bfloat16(z);
    stf(out, idx, z, f32);                  // zin
    stf(out, 2 * NN * CC + idx, mu, f32);   // mu
    stf(out, 3 * NN * CC + idx, lv, f32);   // logvar
}

// ---------------------------------------------------------------------------
// GAT attention scores per (node, head), bf16 HH
// ---------------------------------------------------------------------------
__global__ void att_kernel(const __hip_bfloat16* __restrict__ HHb,
                           const void* __restrict__ att_src, const void* __restrict__ att_dst,
                           float* __restrict__ AS, float* __restrict__ AD,
                           const int* __restrict__ flags)
{
    const int f32 = flags[0];
    int wid  = (blockIdx.x * blockDim.x + threadIdx.x) >> 6;
    int lane = threadIdx.x & 63;
    if (wid >= NN * 2) return;
    int n = wid >> 1, h = wid & 1;
    int base = n * 256 + h * CC;
    float v1 = b2f(HHb[base + lane]), v2 = b2f(HHb[base + lane + 64]);
    float s = v1 * ldf(att_src, h * CC + lane, f32) + v2 * ldf(att_src, h * CC + lane + 64, f32);
    float d = v1 * ldf(att_dst, h * CC + lane, f32) + v2 * ldf(att_dst, h * CC + lane + 64, f32);
#pragma unroll
    for (int off = 32; off; off >>= 1) {
        s += __shfl_down(s, off);
        d += __shfl_down(d, off);
    }
    if (lane == 0) { AS[wid] = s; AD[wid] = d; }
}

// ---------------------------------------------------------------------------
// GAT softmax stats per (node, head) + alpha materialization
// ---------------------------------------------------------------------------
__global__ void gat_stats_kernel(const float* __restrict__ AS, const float* __restrict__ AD,
                                 const int* __restrict__ off, const int* __restrict__ csr,
                                 float* __restrict__ ALPHA, float* __restrict__ SALPHA)
{
    int wid  = (blockIdx.x * blockDim.x + threadIdx.x) >> 6;
    int lane = threadIdx.x & 63;
    if (wid >= NN * 2) return;
    int n = wid >> 1, h = wid & 1;
    int b = off[n], e = off[n + 1];
    float adh = AD[n * 2 + h];
    float self_l = leaky02(AS[n * 2 + h] + adh);
    float m = (lane == 0) ? self_l : NEG_INF;
    for (int i = b + lane; i < e; i += 64) {
        int s = csr[i];
        m = fmaxf(m, leaky02(AS[s * 2 + h] + adh));
    }
#pragma unroll
    for (int o = 32; o; o >>= 1) m = fmaxf(m, __shfl_xor(m, o));
    float sum = (lane == 0) ? expf(self_l - m) : 0.f;
    for (int i = b + lane; i < e; i += 64) {
        int s = csr[i];
        sum += expf(leaky02(AS[s * 2 + h] + adh) - m);
    }
#pragma unroll
    for (int o = 32; o; o >>= 1) sum += __shfl_xor(sum, o);
    float inv = 1.f / sum;
    for (int i = b + lane; i < e; i += 64) {
        int s = csr[i];
        ALPHA[i * 2 + h] = expf(leaky02(AS[s * 2 + h] + adh) - m) * inv;
    }
    if (lane == 0) SALPHA[wid] = expf(self_l - m) * inv;
}

// ---------------------------------------------------------------------------
// GAT aggregation, half-wave per dst: 32 lanes x uint4 = 512 B row;
// alpha pre-materialized; 4-deep unroll (VGPR 32, ~8 waves/SIMD);
// OUT += b_gat fused.
// ---------------------------------------------------------------------------
__global__ __launch_bounds__(256) void gat_agg_kernel(
    const uint4* __restrict__ HH4,
    const float* __restrict__ ALPHA, const float* __restrict__ SALPHA,
    const int* __restrict__ off, const int* __restrict__ csr,
    const void* __restrict__ b_gat, uint4* __restrict__ OUT4,
    const int* __restrict__ flags)
{
    const int f32 = flags[0];
    int hw = (blockIdx.x * blockDim.x + threadIdx.x) >> 5;
    int l5 = threadIdx.x & 31;
    if (hw >= NN) return;
    int d = hw, h = l5 >> 4;
    uint4 wv = HH4[(size_t)d * 32 + l5];
    float a0 = SALPHA[d * 2 + h];
    float4 p = bf4(wv.x, wv.y), q = bf4(wv.z, wv.w);
    float4 accA = make_float4(a0 * p.x, a0 * p.y, a0 * p.z, a0 * p.w);
    float4 accB = make_float4(a0 * q.x, a0 * q.y, a0 * q.z, a0 * q.w);
    int b = off[d], e = off[d + 1];
    int i = b;
    for (; i + 4 <= e; i += 4) {
        uint4 w0 = HH4[(size_t)csr[i]     * 32 + l5];
        uint4 w1 = HH4[(size_t)csr[i + 1] * 32 + l5];
        uint4 w2 = HH4[(size_t)csr[i + 2] * 32 + l5];
        uint4 w3 = HH4[(size_t)csr[i + 3] * 32 + l5];
        float a1 = ALPHA[(i)     * 2 + h];
        float a2 = ALPHA[(i + 1) * 2 + h];
        float a3 = ALPHA[(i + 2) * 2 + h];
        float a4 = ALPHA[(i + 3) * 2 + h];
        float4 f;
        f = bf4(w0.x, w0.y); accA.x += a1 * f.x; accA.y += a1 * f.y; accA.z += a1 * f.z; accA.w += a1 * f.w;
        f = bf4(w0.z, w0.w); accB.x += a1 * f.x; accB.y += a1 * f.y; accB.z += a1 * f.z; accB.w += a1 * f.w;
        f = bf4(w1.x, w1.y); accA.x += a2 * f.x; accA.y += a2 * f.y; accA.z += a2 * f.z; accA.w += a2 * f.w;
        f = bf4(w1.z, w1.w); accB.x += a2 * f.x; accB.y += a2 * f.y; accB.z += a2 * f.z; accB.w += a2 * f.w;
        f = bf4(w2.x, w2.y); accA.x += a3 * f.x; accA.y += a3 * f.y; accA.z += a3 * f.z; accA.w += a3 * f.w;
        f = bf4(w2.z, w2.w); accB.x += a3 * f.x; accB.y += a3 * f.y; accB.z += a3 * f.z; accB.w += a3 * f.w;
        f = bf4(w3.x, w3.y); accA.x += a4 * f.x; accA.y += a4 * f.y; accA.z += a4 * f.z; accA.w += a4 * f.w;
        f = bf4(w3.z, w3.w); accB.x += a4 * f.x; accB.y += a4 * f.y; accB.z += a4 * f.z; accB.w += a4 * f.w;
    }
    for (; i < e; i++) {
        uint4 w = HH4[(size_t)csr[i] * 32 + l5];
        float al = ALPHA[i * 2 + h];
        float4 f = bf4(w.x, w.y);
        accA.x += al * f.x; accA.y += al * f.y; accA.z += al * f.z; accA.w += al * f.w;
        f = bf4(w.z, w.w);
        accB.x += al * f.x; accB.y += al * f.y; accB.z += al * f.z; accB.w += al * f.w;
    }
    int c0 = 8 * l5;
    accA.x += ldf(b_gat, c0 + 0, f32); accA.y += ldf(b_gat, c0 + 1, f32);
    accA.z += ldf(b_gat, c0 + 2, f32); accA.w += ldf(b_gat, c0 + 3, f32);
    accB.x += ldf(b_gat, c0 + 4, f32); accB.y += ldf(b_gat, c0 + 5, f32);
    accB.z += ldf(b_gat, c0 + 6, f32); accB.w += ldf(b_gat, c0 + 7, f32);
    uint2 oa = f4bf(accA), ob = f4bf(accB);
    uint4 o; o.x = oa.x; o.y = oa.y; o.z = ob.x; o.w = ob.y;
    OUT4[(size_t)d * 32 + l5] = o;
}

// ---------------------------------------------------------------------------
extern "C" void kernel_launch(void* const* d_in, const int* in_sizes, int n_in,
                              void* d_out, int out_size, void* d_ws, size_t ws_size,
                              hipStream_t stream)
{
    const void* xin    = d_in[0];
    const void* ei     = d_in[1];
    const void* eps    = d_in[2];
    const void* W_emb  = d_in[3];
    const void* b_emb  = d_in[4];
    const void* g_emb  = d_in[5];
    const void* be_emb = d_in[6];
    const void* W1     = d_in[7];
    const void* b1     = d_in[8];
    const void* g1     = d_in[9];
    const void* be1    = d_in[10];
    const void* W2     = d_in[11];
    const void* b2     = d_in[12];
    const void* W_mu   = d_in[13];
    const void* b_mu   = d_in[14];
    const void* W_var  = d_in[15];
    const void* b_var  = d_in[16];
    const void* W_gat  = d_in[17];
    const void* attS   = d_in[18];
    const void* attD   = d_in[19];
    const void* b_gat  = d_in[20];
    const void* W_dec  = d_in[21];
    const void* b_dec  = d_in[22];

    // workspace layout: 4*NB fp32 slots + tail ≈ 53.8 MB
    float* ws = (float*)d_ws;
    const size_t NB = (size_t)NN * CC;       // 2,560,000
    float* B0 = ws;                          // bf16 MULV (N x 256) | bf16 HH
    float* B1 = ws + 1 * NB;                 // bf16 Y | bf16 OUT (N x 256)
    float* B2 = ws + 2 * NB;                 // bf16 Xbf | Hbf
    float* B3 = ws + 3 * NB;                 // bf16 Zbf | Zobf
    __hip_bfloat16* Xbf   = (__hip_bfloat16*)B2;       // N x 128
    __hip_bfloat16* Hbf   = Xbf + NB;                  // N x 128
    __hip_bfloat16* Zbf   = (__hip_bfloat16*)B3;       // N x 128
    __hip_bfloat16* Zobf  = Zbf + NB;                  // N x 128
    __hip_bfloat16* HHbf  = (__hip_bfloat16*)B0;       // N x 256
    __hip_bfloat16* OUTbf = (__hip_bfloat16*)B1;       // N x 256
    __hip_bfloat16* Ybf   = (__hip_bfloat16*)B1;       // N x 128 (BN input)
    __hip_bfloat16* MULV  = (__hip_bfloat16*)B0;       // N x 256 (mu|logvar)
    float* TAIL  = ws + 4 * NB;
    float* AS     = TAIL;                    // 40000
    float* AD     = TAIL + 40000;            // 40000
    float* SALPHA = TAIL + 80000;            // 40000
    int*   FLAGS  = (int*)(TAIL + 120000);   // 16
    int*   BSUM   = FLAGS + 16;              // 128
    int*   BOFF   = BSUM + 128;              // 128
    int*   DEG    = BOFF + 128;              // 20000  <- zeroed
    float* SUMS   = (float*)(DEG + 20000);   // 256 (sums | sumsq)
    float* PART   = SUMS + 256;              // BNB*256 = 32768
    int*   OFF    = (int*)(PART + BNB * 256); // 20008 (padded)
    int*   CUR    = OFF + 20008;             // 20000
    int*   CSR    = CUR + 20000;             // 640000
    float* ALPHA  = (float*)(CSR + 640000);  // 1,280,000
    __hip_bfloat16* WTB = (__hip_bfloat16*)(ALPHA + 1280000);  // 143360 bf16
    __hip_bfloat16* WTemb = WTB;
    __hip_bfloat16* WT1   = WTB + R0_;
    __hip_bfloat16* WT2   = WTB + R1_;
    __hip_bfloat16* WTmuv = WTB + R2_;       // mu|var contiguous -> NC=256
    __hip_bfloat16* WTgat = WTB + R4_;
    __hip_bfloat16* WTdec = WTB + R5_;
    __hip_bfloat16* Xin   = WTB + R6_;       // NN x 96 bf16

    detect_kernel<<<1, 256, 0, stream>>>((const unsigned int*)xin,
                                         (const unsigned int*)ei, FLAGS);

    // -------- merged weight transpose + node-feature conversion --------
    cvt_all_kernel<<<(TCVT + 255) / 256, 256, 0, stream>>>(
        W_emb, W1, W2, W_mu, W_var, W_gat, W_dec, xin, WTB, FLAGS);

    // -------- memset: DEG only --------
    hipMemsetAsync(DEG, 0, 20000 * sizeof(int), stream);

    // -------- CSR build (sorted by destination, XCD-region partitioned) ------
    hist_kernel<<<NCH * 8, 256, 0, stream>>>(ei, DEG, FLAGS);
    scan1_kernel<<<NBS, 256, 0, stream>>>(DEG, BSUM);
    scan2_kernel<<<1, 128, 0, stream>>>(BSUM, BOFF, OFF);
    scan3_kernel<<<NBS, 256, 0, stream>>>(DEG, BOFF, OFF, CUR);
    scatter_kernel<<<NCH * 8, 256, 0, stream>>>(ei, CUR, CSR, FLAGS);

    // -------- Stage A: atom embedding = relu(BN(x @ W_emb + b_emb)) -> Xbf ----
    mfma_gemm_kernel<96, 128, 2, 1><<<NN / 32, 256, 0, stream>>>(
        Xin, WTemb, b_emb, Ybf, 0, FLAGS);
    bn_part_kernel<<<BNB, 256, 0, stream>>>((const unsigned*)Ybf, PART);
    bn_reduce_kernel<<<1, 256, 0, stream>>>(PART, SUMS);
    bn_relu_kernel<<<(NN * 64) / 256, 256, 0, stream>>>(
        (const unsigned*)Ybf, (unsigned*)Xbf, SUMS, SUMS + 128, g_emb, be_emb, FLAGS);

    // -------- Stage B: GIN x2: x = W2( relu(BN(W1(x+agg))) ) --------
    for (int t = 0; t < 2; t++) {
        gin_gather_kernel<<<NN / 8, 256, 0, stream>>>(
            (const uint2*)Xbf, (uint2*)Hbf, OFF, CSR);
        mfma_gemm_kernel<128, 128, 2, 1><<<NN / 32, 256, 0, stream>>>(
            Hbf, WT1, b1, Ybf, 0, FLAGS);
        bn_part_kernel<<<BNB, 256, 0, stream>>>((const unsigned*)Ybf, PART);
        bn_reduce_kernel<<<1, 256, 0, stream>>>(PART, SUMS);
        bn_relu_kernel<<<(NN * 64) / 256, 256, 0, stream>>>(
            (const unsigned*)Ybf, (unsigned*)Hbf, SUMS, SUMS + 128, g1, be1, FLAGS);
        mfma_gemm_kernel<128, 128, 2, 1><<<NN / 32, 256, 0, stream>>>(
            Hbf, WT2, b2, Xbf, 0, FLAGS);
    }

    // -------- Stage C: merged VAE heads (Xbf -> MULV bf16 N x 256) --------
    mfma_gemm_kernel<128, 256, 4, 1><<<NN / 16, 256, 0, stream>>>(
        Xbf, WTmuv, nullptr, MULV, 0, FLAGS);
    z_kernel<<<(NN * CC) / 256, 256, 0, stream>>>(MULV, eps, b_mu, b_var, Zbf, d_out, FLAGS);

    // -------- Stage D: GAT x2; decoder as MFMA GEMM --------
    const __hip_bfloat16* zc = Zbf;
    for (int t = 0; t < 2; t++) {
        mfma_gemm_kernel<128, 256, 4, 1><<<NN / 16, 256, 0, stream>>>(
            zc, WTgat, nullptr, HHbf, 0, FLAGS);
        att_kernel<<<(NN * 2) / 4, 256, 0, stream>>>(HHbf, attS, attD, AS, AD, FLAGS);
        gat_stats_kernel<<<(NN * 2) / 4, 256, 0, stream>>>(AS, AD, OFF, CSR, ALPHA, SALPHA);
        gat_agg_kernel<<<NN / 8, 256, 0, stream>>>(
            (const uint4*)HHbf, ALPHA, SALPHA, OFF, CSR, b_gat, (uint4*)OUTbf, FLAGS);
        if (t == 0) {
            mfma_gemm_kernel<256, 128, 2, 1><<<NN / 32, 256, 0, stream>>>(
                OUTbf, WTdec, b_dec, Zobf, 0, FLAGS);
            zc = Zobf;
        } else {
            mfma_gemm_kernel<256, 128, 2, 2><<<NN / 32, 256, 0, stream>>>(
                OUTbf, WTdec, b_dec, d_out, NN * CC, FLAGS);
        }
    }
}